// Round 1
// baseline (169.694 us; speedup 1.0000x reference)
//
#include <hip/hip_runtime.h>
#include <math.h>

#define N_NODES 131072
#define H 256
#define HH 128
#define B_GRAPHS 512

// ---------------- K1: segment bounds (batch is sorted) ----------------
__global__ void k_seg_bounds(const int* __restrict__ batch, int* __restrict__ seg_start,
                             int N, int B) {
  int b = blockIdx.x * blockDim.x + threadIdx.x;
  if (b > B) return;
  int lo = 0, hi = N;
  while (lo < hi) {
    int mid = (lo + hi) >> 1;
    if (batch[mid] < b) lo = mid + 1; else hi = mid;
  }
  seg_start[b] = lo;
}

// ---------------- K2: score MLP: s = relu(x@W1+b1)@W2 + b2 (fp32) ----------------
// 128-node tile per block, 256 threads, 8x8 register microtile.
__global__ __launch_bounds__(256) void k_score(const float* __restrict__ x,
                                               const float* __restrict__ W1,
                                               const float* __restrict__ b1,
                                               const float* __restrict__ W2,
                                               const float* __restrict__ b2,
                                               float* __restrict__ s_out) {
  __shared__ float xs[32][132];   // [kk][node], stride 132 (16B-aligned, bank-spread)
  __shared__ float ws[32][128];   // [kk][hid]
  const int t = threadIdx.x;
  const int tx = t & 15;          // hidden group: h = tx*8..+8
  const int ty = t >> 4;          // node group:   n = ty*8..+8
  const int node0 = blockIdx.x * 128;

  float acc[8][8];
#pragma unroll
  for (int i = 0; i < 8; ++i)
#pragma unroll
    for (int j = 0; j < 8; ++j) acc[i][j] = 0.f;

  const int lrow = t >> 3;        // 0..31
  const int lcol = (t & 7) << 2;  // 0,4,...,28

  for (int kc = 0; kc < H; kc += 32) {
    // stage x tile transposed: xs[k][node]
#pragma unroll
    for (int p = 0; p < 4; ++p) {
      float4 v = *reinterpret_cast<const float4*>(
          x + (size_t)(node0 + p * 32 + lrow) * H + kc + lcol);
      xs[lcol + 0][p * 32 + lrow] = v.x;
      xs[lcol + 1][p * 32 + lrow] = v.y;
      xs[lcol + 2][p * 32 + lrow] = v.z;
      xs[lcol + 3][p * 32 + lrow] = v.w;
    }
    // stage W1 tile row-major: ws[k][h]
#pragma unroll
    for (int p = 0; p < 4; ++p) {
      *reinterpret_cast<float4*>(&ws[lrow][lcol + p * 32]) =
          *reinterpret_cast<const float4*>(W1 + (size_t)(kc + lrow) * HH + lcol + p * 32);
    }
    __syncthreads();
#pragma unroll
    for (int kk = 0; kk < 32; ++kk) {
      float xa[8], wb[8];
      *reinterpret_cast<float4*>(&xa[0]) = *reinterpret_cast<const float4*>(&xs[kk][ty * 8]);
      *reinterpret_cast<float4*>(&xa[4]) = *reinterpret_cast<const float4*>(&xs[kk][ty * 8 + 4]);
      *reinterpret_cast<float4*>(&wb[0]) = *reinterpret_cast<const float4*>(&ws[kk][tx * 8]);
      *reinterpret_cast<float4*>(&wb[4]) = *reinterpret_cast<const float4*>(&ws[kk][tx * 8 + 4]);
#pragma unroll
      for (int i = 0; i < 8; ++i)
#pragma unroll
        for (int j = 0; j < 8; ++j) acc[i][j] = fmaf(xa[i], wb[j], acc[i][j]);
    }
    __syncthreads();
  }

  // epilogue: relu(hidden + b1) . W2, reduce across the 16 tx groups
  float b1v[8], w2v[8];
#pragma unroll
  for (int j = 0; j < 8; ++j) {
    b1v[j] = b1[tx * 8 + j];
    w2v[j] = W2[tx * 8 + j];  // W2 is [128][1]
  }
  float* red = &ws[0][0];  // reuse ws LDS (need 128*17=2176 <= 4096 floats)
#pragma unroll
  for (int i = 0; i < 8; ++i) {
    float p = 0.f;
#pragma unroll
    for (int j = 0; j < 8; ++j) {
      float h = acc[i][j] + b1v[j];
      p = fmaf(fmaxf(h, 0.f), w2v[j], p);
    }
    red[(ty * 8 + i) * 17 + tx] = p;
  }
  __syncthreads();
  if (t < 128) {
    float sum = b2[0];
#pragma unroll
    for (int q = 0; q < 16; ++q) sum += red[t * 17 + q];
    s_out[node0 + t] = sum;
  }
}

// ---------------- K3: per-segment softmax + mean/attn/max pools ----------------
__global__ __launch_bounds__(512) void k_pool(const float* __restrict__ x,
                                              const float* __restrict__ s,
                                              const int* __restrict__ seg_start,
                                              float* __restrict__ pooled) {
  const int b = blockIdx.x;
  const int t = threadIdx.x;
  const int start = seg_start[b];
  const int end = seg_start[b + 1];
  const int n = end - start;

  __shared__ float sred[512];
  // --- segment max of s
  float m = -INFINITY;
  for (int i = start + t; i < end; i += 512) m = fmaxf(m, s[i]);
  sred[t] = m;
  __syncthreads();
  for (int off = 256; off > 0; off >>= 1) {
    if (t < off) sred[t] = fmaxf(sred[t], sred[t + off]);
    __syncthreads();
  }
  const float smax = sred[0];
  __syncthreads();
  // --- denom = sum exp(s - smax)
  float d = 0.f;
  for (int i = start + t; i < end; i += 512) d += __expf(s[i] - smax);
  sred[t] = d;
  __syncthreads();
  for (int off = 256; off > 0; off >>= 1) {
    if (t < off) sred[t] += sred[t + off];
    __syncthreads();
  }
  const float denom = sred[0];
  __syncthreads();
  const float inv_denom = (denom > 0.f) ? 1.f / denom : 0.f;

  // --- stream x once: mean / attn / max
  const int fq = t & 63;   // feature quad: features fq*4..+4
  const int sub = t >> 6;  // node sub-lane 0..7
  float mean[4] = {0.f, 0.f, 0.f, 0.f};
  float attn[4] = {0.f, 0.f, 0.f, 0.f};
  float mx[4] = {-INFINITY, -INFINITY, -INFINITY, -INFINITY};
  for (int i = start + sub; i < end; i += 8) {
    const float wi = __expf(s[i] - smax);
    const float4 xv = *reinterpret_cast<const float4*>(x + (size_t)i * H + fq * 4);
    mean[0] += xv.x; mean[1] += xv.y; mean[2] += xv.z; mean[3] += xv.w;
    attn[0] = fmaf(xv.x, wi, attn[0]);
    attn[1] = fmaf(xv.y, wi, attn[1]);
    attn[2] = fmaf(xv.z, wi, attn[2]);
    attn[3] = fmaf(xv.w, wi, attn[3]);
    mx[0] = fmaxf(mx[0], xv.x);
    mx[1] = fmaxf(mx[1], xv.y);
    mx[2] = fmaxf(mx[2], xv.z);
    mx[3] = fmaxf(mx[3], xv.w);
  }
  __shared__ float r4[8][264];
  float* po = pooled + (size_t)b * 1024;
  const float invn = 1.f / (float)(n > 0 ? n : 1);
  // mean
  *reinterpret_cast<float4*>(&r4[sub][fq * 4]) = make_float4(mean[0], mean[1], mean[2], mean[3]);
  __syncthreads();
  if (t < 256) {
    float tot = 0.f;
#pragma unroll
    for (int q = 0; q < 8; ++q) tot += r4[q][t];
    po[t] = tot * invn;
  }
  __syncthreads();
  // attn
  *reinterpret_cast<float4*>(&r4[sub][fq * 4]) = make_float4(attn[0], attn[1], attn[2], attn[3]);
  __syncthreads();
  if (t < 256) {
    float tot = 0.f;
#pragma unroll
    for (int q = 0; q < 8; ++q) tot += r4[q][t];
    po[256 + t] = tot * inv_denom;
  }
  __syncthreads();
  // max
  *reinterpret_cast<float4*>(&r4[sub][fq * 4]) = make_float4(mx[0], mx[1], mx[2], mx[3]);
  __syncthreads();
  if (t < 256) {
    float tot = -INFINITY;
#pragma unroll
    for (int q = 0; q < 8; ++q) tot = fmaxf(tot, r4[q][t]);
    po[512 + t] = (n > 0) ? tot : 0.f;
  }
}

// ---------------- K4: per-segment top-k (by s desc, idx asc) mean pool ----------------
__global__ __launch_bounds__(256) void k_topk(const float* __restrict__ x,
                                              const float* __restrict__ s,
                                              const int* __restrict__ seg_start,
                                              float* __restrict__ pooled) {
  const int b = blockIdx.x;
  const int t = threadIdx.x;
  const int start = seg_start[b];
  const int end = seg_start[b + 1];
  const int n = end - start;
  int k = 0;
  if (n > 0) {
    k = (int)ceilf(0.05f * (float)n);  // matches jnp.ceil(f32(0.05)*f32(n))
    if (k < 5) k = 5;
    if (k > 64) k = 64;
    if (k > n) k = n;
  }
  __shared__ float rkey[256];
  __shared__ int ridx[256];
  __shared__ int sel[64];

  // threshold-descent selection: round r finds max key strictly below prev key.
  float pk = INFINITY;
  int pidx = -1;
  for (int r = 0; r < k; ++r) {
    float bk = -INFINITY;
    int bi = 0x7fffffff;
    for (int i = start + t; i < end; i += 256) {
      const float si = s[i];
      const bool below = (si < pk) || (si == pk && i > pidx);
      if (below) {
        if (si > bk || (si == bk && i < bi)) { bk = si; bi = i; }
      }
    }
    rkey[t] = bk; ridx[t] = bi;
    __syncthreads();
    for (int off = 128; off > 0; off >>= 1) {
      if (t < off) {
        const float ok = rkey[t + off];
        const int oi = ridx[t + off];
        if (ok > rkey[t] || (ok == rkey[t] && oi < ridx[t])) { rkey[t] = ok; ridx[t] = oi; }
      }
      __syncthreads();
    }
    pk = rkey[0];
    pidx = ridx[0];
    if (t == 0) sel[r] = pidx;
    __syncthreads();
  }
  // gather-mean the selected rows; thread t = feature t
  float acc = 0.f;
  for (int r = 0; r < k; ++r) acc += x[(size_t)sel[r] * H + t];
  pooled[(size_t)b * 1024 + 768 + t] = (k > 0) ? acc / (float)k : 0.f;
}

// ---------------- K5: final GEMM [512,1024]@[1024,256], split-K=8 ----------------
__global__ __launch_bounds__(256) void k_gemm(const float* __restrict__ pooled,
                                              const float* __restrict__ Wf,
                                              float* __restrict__ gacc) {
  const int t = threadIdx.x;
  const int r0 = blockIdx.x * 8;
  const int kc0 = blockIdx.y * 128;
  __shared__ float ps[8][132];
  {
    const int r = t >> 5;
    const int c = (t & 31) << 2;
    *reinterpret_cast<float4*>(&ps[r][c]) =
        *reinterpret_cast<const float4*>(pooled + (size_t)(r0 + r) * 1024 + kc0 + c);
  }
  __syncthreads();
  float acc[8];
#pragma unroll
  for (int r = 0; r < 8; ++r) acc[r] = 0.f;
#pragma unroll 4
  for (int c = 0; c < 128; ++c) {
    const float wf = Wf[(size_t)(kc0 + c) * 256 + t];
#pragma unroll
    for (int r = 0; r < 8; ++r) acc[r] = fmaf(ps[r][c], wf, acc[r]);
  }
  float* go = gacc + ((size_t)blockIdx.y * B_GRAPHS + r0) * 256;
#pragma unroll
  for (int r = 0; r < 8; ++r) go[r * 256 + t] = acc[r];
}

// ---------------- K6: reduce split-K + bias + relu -> out ----------------
__global__ __launch_bounds__(256) void k_out(const float* __restrict__ gacc,
                                             const float* __restrict__ bf,
                                             float* __restrict__ out) {
  const int i = blockIdx.x * 256 + threadIdx.x;
  float v = bf[i & 255];
#pragma unroll
  for (int ks = 0; ks < 8; ++ks) v += gacc[(size_t)ks * (B_GRAPHS * 256) + i];
  out[i] = fmaxf(v, 0.f);
}

extern "C" void kernel_launch(void* const* d_in, const int* in_sizes, int n_in,
                              void* d_out, int out_size, void* d_ws, size_t ws_size,
                              hipStream_t stream) {
  const float* x  = (const float*)d_in[0];
  const int* batch = (const int*)d_in[1];
  const float* W1 = (const float*)d_in[2];
  const float* b1 = (const float*)d_in[3];
  const float* W2 = (const float*)d_in[4];
  const float* b2 = (const float*)d_in[5];
  const float* Wf = (const float*)d_in[6];
  const float* bf = (const float*)d_in[7];
  const int N = in_sizes[1];     // 131072
  const int B = B_GRAPHS;        // 512 (num_graphs is fixed by the problem)

  // workspace layout (floats): s[N] | seg_start[1024 ints] | pooled[B*1024] | gacc[8*B*256]
  float* ws = (float*)d_ws;
  float* s = ws;
  int* seg_start = (int*)(ws + N);
  float* pooled = ws + N + 1024;
  float* gacc = pooled + (size_t)B * 1024;

  k_seg_bounds<<<dim3((B + 1 + 255) / 256), dim3(256), 0, stream>>>(batch, seg_start, N, B);
  k_score<<<dim3(N / 128), dim3(256), 0, stream>>>(x, W1, b1, W2, b2, s);
  k_pool<<<dim3(B), dim3(512), 0, stream>>>(x, s, seg_start, pooled);
  k_topk<<<dim3(B), dim3(256), 0, stream>>>(x, s, seg_start, pooled);
  k_gemm<<<dim3(B / 8, 8), dim3(256), 0, stream>>>(pooled, Wf, gacc);
  k_out<<<dim3((B * 256) / 256), dim3(256), 0, stream>>>(gacc, bf, (float*)d_out);
}

// Round 2
// 129.805 us; speedup vs baseline: 1.3073x; 1.3073x over previous
//
#include <hip/hip_runtime.h>
#include <math.h>

#define N_NODES 131072
#define H 256
#define HH 128
#define B_GRAPHS 512

typedef __attribute__((ext_vector_type(8))) short bfrag8;
typedef __attribute__((ext_vector_type(4))) short s16x4;
typedef __attribute__((ext_vector_type(16))) float f32x16;

__device__ __forceinline__ float bfhi(float v) {
  return __builtin_bit_cast(float, __builtin_bit_cast(unsigned, v) & 0xFFFF0000u);
}

// ---------------- K0: pre-split W1 into 3 bf16 planes, transposed [s][col][k] ----------------
__global__ void k_prep_w1(const float* __restrict__ W1, ushort* __restrict__ W1s) {
  const int idx = blockIdx.x * 256 + threadIdx.x;  // 32768 = 256*128
  const int k = idx >> 7, c = idx & 127;
  const float v = W1[idx];
  const float h1 = bfhi(v);
  const float r = v - h1;
  const float h2 = bfhi(r);
  const float r2 = r - h2;
  W1s[0 * 32768 + c * 256 + k] = (ushort)(__builtin_bit_cast(unsigned, v) >> 16);
  W1s[1 * 32768 + c * 256 + k] = (ushort)(__builtin_bit_cast(unsigned, r) >> 16);
  W1s[2 * 32768 + c * 256 + k] = (ushort)(__builtin_bit_cast(unsigned, r2) >> 16);
}

// ---------------- K1: segment bounds (batch is sorted) ----------------
__global__ void k_seg_bounds(const int* __restrict__ batch, int* __restrict__ seg_start,
                             int N, int B) {
  int b = blockIdx.x * blockDim.x + threadIdx.x;
  if (b > B) return;
  int lo = 0, hi = N;
  while (lo < hi) {
    int mid = (lo + hi) >> 1;
    if (batch[mid] < b) lo = mid + 1; else hi = mid;
  }
  seg_start[b] = lo;
}

// ---------------- K2: score MLP via split-bf16 MFMA ----------------
// block = 128 nodes x 128 hidden, 4 waves in 2x2 (wave tile 64x64, 2x2 frags of 32x32x16).
#define PROD(sa, sb)                                                                        \
  do {                                                                                      \
    acc[0][0] = __builtin_amdgcn_mfma_f32_32x32x16_bf16(af[sa][0], bf_[sb][0], acc[0][0],   \
                                                        0, 0, 0);                           \
    acc[0][1] = __builtin_amdgcn_mfma_f32_32x32x16_bf16(af[sa][0], bf_[sb][1], acc[0][1],   \
                                                        0, 0, 0);                           \
    acc[1][0] = __builtin_amdgcn_mfma_f32_32x32x16_bf16(af[sa][1], bf_[sb][0], acc[1][0],   \
                                                        0, 0, 0);                           \
    acc[1][1] = __builtin_amdgcn_mfma_f32_32x32x16_bf16(af[sa][1], bf_[sb][1], acc[1][1],   \
                                                        0, 0, 0);                           \
  } while (0)

__global__ __launch_bounds__(256, 2) void k_score_mfma(
    const float* __restrict__ x, const ushort* __restrict__ W1s,
    const float* __restrict__ b1, const float* __restrict__ W2,
    const float* __restrict__ b2, float* __restrict__ s_out) {
  __shared__ ushort smem[30720];  // A[3][128][40] | B[3][128][40]  (61440 B)
  ushort* Au = smem;
  ushort* Bu = smem + 15360;
  const int t = threadIdx.x;
  const int lane = t & 63;
  const int w = t >> 6;
  const int wr = w >> 1, wc = w & 1;
  const int nl = lane & 31, g = lane >> 5;
  const int node0 = blockIdx.x * 128;

  const f32x16 zero = (f32x16)0.0f;
  f32x16 acc[2][2];
  acc[0][0] = zero; acc[0][1] = zero; acc[1][0] = zero; acc[1][1] = zero;

  const int arow = t >> 3;        // 0..31
  const int ak = (t & 7) * 4;     // 0,4,...,28

  float4 xv[4], xn[4];
#pragma unroll
  for (int q = 0; q < 4; ++q)
    xv[q] = *(const float4*)(x + (size_t)(node0 + q * 32 + arow) * H + ak);
  bfrag8 bw[6], bn[6];
#pragma unroll
  for (int q = 0; q < 6; ++q) {
    const int cid = q * 256 + t;
    const int s = cid >> 9, col = (cid >> 2) & 127, kq = cid & 3;
    bw[q] = *(const bfrag8*)(W1s + s * 32768 + col * 256 + kq * 8);
  }

  for (int kc = 0; kc < H; kc += 32) {
    // ---- stage A (split on the fly) ----
#pragma unroll
    for (int q = 0; q < 4; ++q) {
      const int row = q * 32 + arow;
      float vals[4] = {xv[q].x, xv[q].y, xv[q].z, xv[q].w};
      s16x4 p1, p2, p3;
#pragma unroll
      for (int e = 0; e < 4; ++e) {
        const float v = vals[e];
        const float r = v - bfhi(v);
        const float r2 = r - bfhi(r);
        p1[e] = (short)(__builtin_bit_cast(unsigned, v) >> 16);
        p2[e] = (short)(__builtin_bit_cast(unsigned, r) >> 16);
        p3[e] = (short)(__builtin_bit_cast(unsigned, r2) >> 16);
      }
      *(s16x4*)&Au[0 * 5120 + row * 40 + ak] = p1;
      *(s16x4*)&Au[1 * 5120 + row * 40 + ak] = p2;
      *(s16x4*)&Au[2 * 5120 + row * 40 + ak] = p3;
    }
    // ---- stage B (pre-split, from L2/L3) ----
#pragma unroll
    for (int q = 0; q < 6; ++q) {
      const int cid = q * 256 + t;
      const int s = cid >> 9, col = (cid >> 2) & 127, kq = cid & 3;
      *(bfrag8*)&Bu[s * 5120 + col * 40 + kq * 8] = bw[q];
    }
    __syncthreads();
    // ---- prefetch next tile while MFMAs run ----
    if (kc + 32 < H) {
#pragma unroll
      for (int q = 0; q < 4; ++q)
        xn[q] = *(const float4*)(x + (size_t)(node0 + q * 32 + arow) * H + kc + 32 + ak);
#pragma unroll
      for (int q = 0; q < 6; ++q) {
        const int cid = q * 256 + t;
        const int s = cid >> 9, col = (cid >> 2) & 127, kq = cid & 3;
        bn[q] = *(const bfrag8*)(W1s + s * 32768 + col * 256 + kc + 32 + kq * 8);
      }
    }
    // ---- MFMA: 6 split-products, 2 K-substeps ----
#pragma unroll
    for (int k0 = 0; k0 < 32; k0 += 16) {
      bfrag8 af[3][2], bf_[3][2];
#pragma unroll
      for (int s = 0; s < 3; ++s) {
#pragma unroll
        for (int i = 0; i < 2; ++i)
          af[s][i] = *(const bfrag8*)&Au[s * 5120 + (wr * 64 + i * 32 + nl) * 40 + k0 + g * 8];
#pragma unroll
        for (int j = 0; j < 2; ++j)
          bf_[s][j] = *(const bfrag8*)&Bu[s * 5120 + (wc * 64 + j * 32 + nl) * 40 + k0 + g * 8];
      }
      PROD(0, 0); PROD(1, 0); PROD(0, 1); PROD(1, 1); PROD(2, 0); PROD(0, 2);
    }
    __syncthreads();
#pragma unroll
    for (int q = 0; q < 4; ++q) xv[q] = xn[q];
#pragma unroll
    for (int q = 0; q < 6; ++q) bw[q] = bn[q];
  }

  // ---- epilogue: layer 2 in fp32 ----
  float* part = (float*)smem;  // [128][64]
  const int col0 = wc * 64 + nl;
  const float b1v0 = b1[col0], b1v1 = b1[col0 + 32];
  const float w2v0 = W2[col0], w2v1 = W2[col0 + 32];
#pragma unroll
  for (int i = 0; i < 2; ++i) {
#pragma unroll
    for (int r = 0; r < 16; ++r) {
      const int nodeL = wr * 64 + i * 32 + (r & 3) + 8 * (r >> 2) + 4 * g;
      const float h0 = acc[i][0][r] + b1v0;
      const float h1 = acc[i][1][r] + b1v1;
      const float p = fmaxf(h0, 0.f) * w2v0 + fmaxf(h1, 0.f) * w2v1;
      part[nodeL * 64 + wc * 32 + nl] = p;
    }
  }
  __syncthreads();
  if (t < 128) {
    float sv = b2[0];
#pragma unroll 8
    for (int cc = 0; cc < 64; ++cc) {
      const int c2 = (cc + t) & 63;
      sv += part[t * 64 + c2];
    }
    s_out[node0 + t] = sv;
  }
}

// ---------------- K3: per-segment softmax + mean/attn/max pools ----------------
__global__ __launch_bounds__(512) void k_pool(const float* __restrict__ x,
                                              const float* __restrict__ s,
                                              const int* __restrict__ seg_start,
                                              float* __restrict__ pooled) {
  const int b = blockIdx.x;
  const int t = threadIdx.x;
  const int start = seg_start[b];
  const int end = seg_start[b + 1];
  const int n = end - start;

  __shared__ float sred[512];
  float m = -INFINITY;
  for (int i = start + t; i < end; i += 512) m = fmaxf(m, s[i]);
  sred[t] = m;
  __syncthreads();
  for (int off = 256; off > 0; off >>= 1) {
    if (t < off) sred[t] = fmaxf(sred[t], sred[t + off]);
    __syncthreads();
  }
  const float smax = sred[0];
  __syncthreads();
  float d = 0.f;
  for (int i = start + t; i < end; i += 512) d += __expf(s[i] - smax);
  sred[t] = d;
  __syncthreads();
  for (int off = 256; off > 0; off >>= 1) {
    if (t < off) sred[t] += sred[t + off];
    __syncthreads();
  }
  const float denom = sred[0];
  __syncthreads();
  const float inv_denom = (denom > 0.f) ? 1.f / denom : 0.f;

  const int fq = t & 63;
  const int sub = t >> 6;
  float mean[4] = {0.f, 0.f, 0.f, 0.f};
  float attn[4] = {0.f, 0.f, 0.f, 0.f};
  float mx[4] = {-INFINITY, -INFINITY, -INFINITY, -INFINITY};
  for (int i = start + sub; i < end; i += 8) {
    const float wi = __expf(s[i] - smax);
    const float4 xv = *reinterpret_cast<const float4*>(x + (size_t)i * H + fq * 4);
    mean[0] += xv.x; mean[1] += xv.y; mean[2] += xv.z; mean[3] += xv.w;
    attn[0] = fmaf(xv.x, wi, attn[0]);
    attn[1] = fmaf(xv.y, wi, attn[1]);
    attn[2] = fmaf(xv.z, wi, attn[2]);
    attn[3] = fmaf(xv.w, wi, attn[3]);
    mx[0] = fmaxf(mx[0], xv.x);
    mx[1] = fmaxf(mx[1], xv.y);
    mx[2] = fmaxf(mx[2], xv.z);
    mx[3] = fmaxf(mx[3], xv.w);
  }
  __shared__ float r4[8][264];
  float* po = pooled + (size_t)b * 1024;
  const float invn = 1.f / (float)(n > 0 ? n : 1);
  *reinterpret_cast<float4*>(&r4[sub][fq * 4]) = make_float4(mean[0], mean[1], mean[2], mean[3]);
  __syncthreads();
  if (t < 256) {
    float tot = 0.f;
#pragma unroll
    for (int q = 0; q < 8; ++q) tot += r4[q][t];
    po[t] = tot * invn;
  }
  __syncthreads();
  *reinterpret_cast<float4*>(&r4[sub][fq * 4]) = make_float4(attn[0], attn[1], attn[2], attn[3]);
  __syncthreads();
  if (t < 256) {
    float tot = 0.f;
#pragma unroll
    for (int q = 0; q < 8; ++q) tot += r4[q][t];
    po[256 + t] = tot * inv_denom;
  }
  __syncthreads();
  *reinterpret_cast<float4*>(&r4[sub][fq * 4]) = make_float4(mx[0], mx[1], mx[2], mx[3]);
  __syncthreads();
  if (t < 256) {
    float tot = -INFINITY;
#pragma unroll
    for (int q = 0; q < 8; ++q) tot = fmaxf(tot, r4[q][t]);
    po[512 + t] = (n > 0) ? tot : 0.f;
  }
}

// ---------------- K4: per-segment top-k (by s desc, idx asc) mean pool ----------------
__global__ __launch_bounds__(256) void k_topk(const float* __restrict__ x,
                                              const float* __restrict__ s,
                                              const int* __restrict__ seg_start,
                                              float* __restrict__ pooled) {
  const int b = blockIdx.x;
  const int t = threadIdx.x;
  const int start = seg_start[b];
  const int end = seg_start[b + 1];
  const int n = end - start;
  int k = 0;
  if (n > 0) {
    k = (int)ceilf(0.05f * (float)n);
    if (k < 5) k = 5;
    if (k > 64) k = 64;
    if (k > n) k = n;
  }
  __shared__ float rkey[256];
  __shared__ int ridx[256];
  __shared__ int sel[64];

  float pk = INFINITY;
  int pidx = -1;
  for (int r = 0; r < k; ++r) {
    float bk = -INFINITY;
    int bi = 0x7fffffff;
    for (int i = start + t; i < end; i += 256) {
      const float si = s[i];
      const bool below = (si < pk) || (si == pk && i > pidx);
      if (below) {
        if (si > bk || (si == bk && i < bi)) { bk = si; bi = i; }
      }
    }
    rkey[t] = bk; ridx[t] = bi;
    __syncthreads();
    for (int off = 128; off > 0; off >>= 1) {
      if (t < off) {
        const float ok = rkey[t + off];
        const int oi = ridx[t + off];
        if (ok > rkey[t] || (ok == rkey[t] && oi < ridx[t])) { rkey[t] = ok; ridx[t] = oi; }
      }
      __syncthreads();
    }
    pk = rkey[0];
    pidx = ridx[0];
    if (t == 0) sel[r] = pidx;
    __syncthreads();
  }
  float acc = 0.f;
  for (int r = 0; r < k; ++r) acc += x[(size_t)sel[r] * H + t];
  pooled[(size_t)b * 1024 + 768 + t] = (k > 0) ? acc / (float)k : 0.f;
}

// ---------------- K5: final GEMM [512,1024]@[1024,256], split-K=8 ----------------
__global__ __launch_bounds__(256) void k_gemm(const float* __restrict__ pooled,
                                              const float* __restrict__ Wf,
                                              float* __restrict__ gacc) {
  const int t = threadIdx.x;
  const int r0 = blockIdx.x * 8;
  const int kc0 = blockIdx.y * 128;
  __shared__ float ps[8][132];
  {
    const int r = t >> 5;
    const int c = (t & 31) << 2;
    *reinterpret_cast<float4*>(&ps[r][c]) =
        *reinterpret_cast<const float4*>(pooled + (size_t)(r0 + r) * 1024 + kc0 + c);
  }
  __syncthreads();
  float acc[8];
#pragma unroll
  for (int r = 0; r < 8; ++r) acc[r] = 0.f;
#pragma unroll 4
  for (int c = 0; c < 128; ++c) {
    const float wf = Wf[(size_t)(kc0 + c) * 256 + t];
#pragma unroll
    for (int r = 0; r < 8; ++r) acc[r] = fmaf(ps[r][c], wf, acc[r]);
  }
  float* go = gacc + ((size_t)blockIdx.y * B_GRAPHS + r0) * 256;
#pragma unroll
  for (int r = 0; r < 8; ++r) go[r * 256 + t] = acc[r];
}

// ---------------- K6: reduce split-K + bias + relu -> out ----------------
__global__ __launch_bounds__(256) void k_out(const float* __restrict__ gacc,
                                             const float* __restrict__ bf,
                                             float* __restrict__ out) {
  const int i = blockIdx.x * 256 + threadIdx.x;
  float v = bf[i & 255];
#pragma unroll
  for (int ks = 0; ks < 8; ++ks) v += gacc[(size_t)ks * (B_GRAPHS * 256) + i];
  out[i] = fmaxf(v, 0.f);
}

extern "C" void kernel_launch(void* const* d_in, const int* in_sizes, int n_in,
                              void* d_out, int out_size, void* d_ws, size_t ws_size,
                              hipStream_t stream) {
  const float* x  = (const float*)d_in[0];
  const int* batch = (const int*)d_in[1];
  const float* W1 = (const float*)d_in[2];
  const float* b1 = (const float*)d_in[3];
  const float* W2 = (const float*)d_in[4];
  const float* b2 = (const float*)d_in[5];
  const float* Wf = (const float*)d_in[6];
  const float* bf = (const float*)d_in[7];
  const int N = in_sizes[1];     // 131072
  const int B = B_GRAPHS;

  // ws floats: s[N] | seg_start[1024 ints] | pooled[B*1024] | gacc[8*B*256] | W1s[3*128*256 u16]
  float* ws = (float*)d_ws;
  float* s = ws;
  int* seg_start = (int*)(ws + N);
  float* pooled = ws + N + 1024;
  float* gacc = pooled + (size_t)B * 1024;
  ushort* W1s = (ushort*)(gacc + (size_t)8 * B * 256);

  k_prep_w1<<<dim3(128), dim3(256), 0, stream>>>(W1, W1s);
  k_seg_bounds<<<dim3((B + 1 + 255) / 256), dim3(256), 0, stream>>>(batch, seg_start, N, B);
  k_score_mfma<<<dim3(N / 128), dim3(256), 0, stream>>>(x, W1s, b1, W2, b2, s);
  k_pool<<<dim3(B), dim3(512), 0, stream>>>(x, s, seg_start, pooled);
  k_topk<<<dim3(B), dim3(256), 0, stream>>>(x, s, seg_start, pooled);
  k_gemm<<<dim3(B / 8, 8), dim3(256), 0, stream>>>(pooled, Wf, gacc);
  k_out<<<dim3((B * 256) / 256), dim3(256), 0, stream>>>(gacc, bf, (float*)d_out);
}